// Round 2
// baseline (1278.871 us; speedup 1.0000x reference)
//
#include <hip/hip_runtime.h>
#include <hip/hip_bf16.h>
#include <cstdint>

// Problem dims (fixed by the reference)
#define B_   8192
#define D_   1024
#define O_   1024
#define HE_  2048
#define NN_  7     // decision nodes
#define NL_  8     // leaves / experts
#define HR_  32    // router hidden
#define RC_  224   // NN_*HR_
#define K3_  3072  // router split-GEMM K (hi|hi|lo)

typedef __attribute__((ext_vector_type(2))) float f32x2;
typedef __attribute__((ext_vector_type(4))) float f32x4;
typedef __attribute__((ext_vector_type(8))) short bf16x8;
typedef __attribute__((ext_vector_type(4))) unsigned short u16x4;
typedef unsigned short u16;
typedef unsigned int u32;

__device__ __forceinline__ u16 f2bf(float f) {
  __hip_bfloat16 h = __float2bfloat16(f);
  return *reinterpret_cast<u16*>(&h);
}
__device__ __forceinline__ float bf2f(u16 u) {
  u32 v = ((u32)u) << 16;
  return *reinterpret_cast<float*>(&v);
}
__device__ __forceinline__ float gelu_exact(float v) {
  return 0.5f * v * (1.0f + erff(v * 0.7071067811865475f));
}
__device__ __forceinline__ void gload16(const void* g, void* l) {
  __builtin_amdgcn_global_load_lds(
      (const __attribute__((address_space(1))) void*)(uintptr_t)g,
      (__attribute__((address_space(3))) void*)(uintptr_t)l,
      16, 0, 0);
}

// ---- Xb3[b][3072] = [bf16(x) | bf16(x) | bf16(x - bf16(x))] ---------------
__global__ __launch_bounds__(256) void build_xb3_kernel(
    const float* __restrict__ in, u16* __restrict__ out) {
  size_t i = ((size_t)blockIdx.x * 256 + threadIdx.x) * 4;
  size_t row = i >> 10;
  int col = (int)(i & 1023);
  f32x4 f = *reinterpret_cast<const f32x4*>(in + i);
  u16x4 hi, lo;
#pragma unroll
  for (int j = 0; j < 4; j++) {
    hi[j] = f2bf(f[j]);
    lo[j] = f2bf(f[j] - bf2f(hi[j]));
  }
  u16* base = out + row * (size_t)K3_ + col;
  *reinterpret_cast<u16x4*>(base)        = hi;
  *reinterpret_cast<u16x4*>(base + 1024) = hi;
  *reinterpret_cast<u16x4*>(base + 2048) = lo;
}

// ---- Wr3[256][3072]: rows c<224 = [w_hi | w_lo | w_hi] of rW1[n][k][h] ----
__global__ __launch_bounds__(256) void build_wr3_kernel(
    const float* __restrict__ rW1, u16* __restrict__ Wr3) {
  size_t i = ((size_t)blockIdx.x * 256 + threadIdx.x) * 4;  // over 256*3072
  int c = (int)(i / K3_), k = (int)(i % K3_);
  int j = k >> 10, kk = k & 1023;
  u16x4 o;
  if (c < RC_) {
    int node = c >> 5, h = c & 31;
    const float* src = rW1 + ((size_t)node * 1024 + kk) * HR_ + h;
#pragma unroll
    for (int t = 0; t < 4; t++) {
      float f = src[t * HR_];
      u16 hi = f2bf(f);
      o[t] = (j == 1) ? f2bf(f - bf2f(hi)) : hi;
    }
  } else {
    o[0] = 0; o[1] = 0; o[2] = 0; o[3] = 0;
  }
  *reinterpret_cast<u16x4*>(Wr3 + i) = o;
}

// ------------- transpose + cvt: out[c*ldo + r] (+e*out_estride) = in[r][c] --
__global__ __launch_bounds__(256) void transpose_cvt_kernel(
    const float* __restrict__ in, u16* __restrict__ out,
    int R, int C, int ldo, long in_estride, long out_estride) {
  __shared__ __attribute__((aligned(16))) float tile[64][65];
  const float* in_e = in + (long)blockIdx.z * in_estride;
  u16* out_e = out + (long)blockIdx.z * out_estride;
  int t = threadIdx.x;
  int r0 = blockIdx.y * 64, c0 = blockIdx.x * 64;
  int cc = t & 63, rbase = t >> 6;
#pragma unroll
  for (int i = 0; i < 16; i++) {
    int rr = rbase + i * 4;
    tile[rr][cc] = in_e[(long)(r0 + rr) * C + c0 + cc];
  }
  __syncthreads();
  int r2 = (t & 31) * 2, cj = t >> 5;
#pragma unroll
  for (int i = 0; i < 8; i++) {
    int c = cj * 8 + i;
    u32 u = (u32)f2bf(tile[r2][c]) | ((u32)f2bf(tile[r2 + 1][c]) << 16);
    *reinterpret_cast<u32*>(out_e + (long)(c0 + c) * ldo + r0 + r2) = u;
  }
}

// ---- router GEMM (m97 128x128 structure): H1 = gelu(Xb3 @ Wr3^T + rb1) ----
// M=8192, N=256(224 used), K=3072; f32-equivalent via bf16 split terms.
__global__ __launch_bounds__(256, 2) void router_gemm_kernel(
    const u16* __restrict__ A, const u16* __restrict__ Bm,
    const float* __restrict__ rb1, float* __restrict__ H1) {
  __shared__ __attribute__((aligned(16))) u16 lA[128 * 32];
  __shared__ __attribute__((aligned(16))) u16 lB[128 * 32];
  int tid = threadIdx.x;
  int gid = blockIdx.x;
  int cpx = gridDim.x >> 3;
  gid = (gid & 7) * cpx + (gid >> 3);
  int bandsz = 2 * 8;
  int band = gid / bandsz, inb = gid % bandsz;
  long m0 = (long)(band * 8 + (inb & 7)) * 128;
  long n0 = (long)(inb >> 3) * 128;
  int wid = tid >> 6, lane = tid & 63;
  int wm = wid >> 1, wn = wid & 1;
  f32x4 acc[4][4];
#pragma unroll
  for (int m = 0; m < 4; m++)
#pragma unroll
    for (int n = 0; n < 4; n++) acc[m][n] = (f32x4){0.f, 0.f, 0.f, 0.f};
  int lr = lane & 15, lk = (lane >> 4) * 8;
  int srow = tid >> 2, soff = (tid & 3) * 8;
  const u16* Ab = A + m0 * K3_;
  const u16* Bb = Bm + n0 * K3_;
  for (int k0 = 0; k0 < K3_; k0 += 32) {
    gload16(Ab + (long)srow * K3_ + k0 + soff, &lA[tid * 8]);
    gload16(Ab + (long)(64 + srow) * K3_ + k0 + soff, &lA[(256 + tid) * 8]);
    gload16(Bb + (long)srow * K3_ + k0 + soff, &lB[tid * 8]);
    gload16(Bb + (long)(64 + srow) * K3_ + k0 + soff, &lB[(256 + tid) * 8]);
    __syncthreads();
    bf16x8 af[4], bfr[4];
#pragma unroll
    for (int m = 0; m < 4; m++)
      af[m] = *reinterpret_cast<const bf16x8*>(&lA[(wm * 64 + m * 16 + lr) * 32 + lk]);
#pragma unroll
    for (int n = 0; n < 4; n++)
      bfr[n] = *reinterpret_cast<const bf16x8*>(&lB[(wn * 64 + n * 16 + lr) * 32 + lk]);
#pragma unroll
    for (int m = 0; m < 4; m++)
#pragma unroll
      for (int n = 0; n < 4; n++)
        acc[m][n] = __builtin_amdgcn_mfma_f32_16x16x32_bf16(af[m], bfr[n], acc[m][n], 0, 0, 0);
    __syncthreads();
  }
  int lq = lane >> 4;
#pragma unroll
  for (int m = 0; m < 4; m++)
#pragma unroll
    for (int n = 0; n < 4; n++)
#pragma unroll
      for (int j = 0; j < 4; j++) {
        long row = m0 + wm * 64 + m * 16 + lq * 4 + j;
        long col = n0 + wn * 64 + n * 16 + lr;
        if (col < RC_)
          H1[row * RC_ + col] = gelu_exact(acc[m][n][j] + rb1[col]);
      }
}

// -------- router layer 2 + softmax + path products + top-k + renorm --------
__global__ __launch_bounds__(256) void router_logits_kernel(
    const float* __restrict__ H1, const float* __restrict__ rW2,
    const float* __restrict__ rb2, const int* __restrict__ topk_ptr,
    float* __restrict__ P) {
  int b = blockIdx.x * 256 + threadIdx.x;
  const float* hrow = H1 + (long)b * RC_;
  float dec[NN_][2];
#pragma unroll
  for (int n = 0; n < NN_; n++) {
    float l0 = rb2[n * 2], l1 = rb2[n * 2 + 1];
#pragma unroll
    for (int r4 = 0; r4 < HR_; r4 += 4) {
      f32x4 h = *reinterpret_cast<const f32x4*>(hrow + n * HR_ + r4);
#pragma unroll
      for (int j = 0; j < 4; j++) {
        l0 += h[j] * rW2[(n * HR_ + r4 + j) * 2];
        l1 += h[j] * rW2[(n * HR_ + r4 + j) * 2 + 1];
      }
    }
    float mx = fmaxf(l0, l1);
    float e0 = expf(l0 - mx), e1 = expf(l1 - mx);
    float s = e0 + e1;
    dec[n][0] = e0 / s; dec[n][1] = e1 / s;
  }
  float v[NL_];
#pragma unroll
  for (int L = 0; L < NL_; L++)
    v[L] = dec[0][L >> 2] * dec[1 + (L >> 2)][(L >> 1) & 1] * dec[3 + (L >> 1)][L & 1];
  int tk = *topk_ptr;
  float p[NL_];
  if (tk < NL_) {
    float s = 0.f;
    bool keep[NL_];
#pragma unroll
    for (int e = 0; e < NL_; e++) {
      int rank = 0;
#pragma unroll
      for (int j = 0; j < NL_; j++)
        rank += ((v[j] > v[e]) || (v[j] == v[e] && j < e)) ? 1 : 0;
      keep[e] = rank < tk;
      if (keep[e]) s += v[e];
    }
    float inv = 1.f / (s + 1e-8f);
#pragma unroll
    for (int e = 0; e < NL_; e++) p[e] = keep[e] ? v[e] * inv : 0.f;
  } else {
#pragma unroll
    for (int e = 0; e < NL_; e++) p[e] = v[e];
  }
#pragma unroll
  for (int e = 0; e < NL_; e++) P[(long)b * NL_ + e] = p[e];
}

// =================== 256x256 8-phase bf16 GEMM (T2+T3+T4+T5) ===============
// BM=BN=256, BK=64, 8 waves (2M x 4N), 128KiB dbuf LDS, XOR-swizzle (r&7) on
// pre-swizzled global source + ds_read side (linear global_load_lds dest).
// MODE 0: out bf16 = bf16( gelu(acc + bias[col+ncol_off]) * P[row][expert] )
// MODE 1: out f32 Ypart[sid][row][col] = acc           (split-K partials)
// MODE 2: out f32 y[row][col] = (accum? y : 0) + acc + p*eb2 bias
template<int MODE>
__global__ __launch_bounds__(512, 2) void gemm8p_kernel(
    const u16* __restrict__ A, const u16* __restrict__ Bm,
    const float* __restrict__ biasv, const float* __restrict__ P,
    void* __restrict__ outp, int lda, int ldb,
    int tiles_m, int tiles_n, int ldo, int ncol_off,
    int expert, int accum, int k_len) {
  __shared__ __attribute__((aligned(16))) u16 lA[2][256 * 64];
  __shared__ __attribute__((aligned(16))) u16 lB[2][256 * 64];
  int tid = threadIdx.x;
  int gid = blockIdx.x;
  int cpx = gridDim.x >> 3;
  gid = (gid & 7) * cpx + (gid >> 3);         // bijective XCD swizzle (grid%8==0)
  int per_split = tiles_m * tiles_n;
  int sid = gid / per_split;
  int rem = gid % per_split;
  int bandsz = tiles_n * 8;
  int band = rem / bandsz, inb = rem % bandsz;
  long m0 = (long)(band * 8 + (inb & 7)) * 256;
  long n0 = (long)(inb >> 3) * 256;
  int wid = tid >> 6, lane = tid & 63;
  int wm = wid >> 2, wn = wid & 3;
  int lr = lane & 15, lkg = lane >> 4;

  f32x4 acc[8][4];
#pragma unroll
  for (int m = 0; m < 8; m++)
#pragma unroll
    for (int n = 0; n < 4; n++) acc[m][n] = (f32x4){0.f, 0.f, 0.f, 0.f};

  // staging: 4 A-loads + 4 B-loads of 16B/thread per K-tile; linear LDS dest,
  // source column pre-swizzled: cs = c16 ^ (r&7)  (same involution on reads)
  long offA[4], offB[4];
  int ldsoff[4];
#pragma unroll
  for (int i = 0; i < 4; i++) {
    int idx = tid + i * 512;
    int r = idx >> 3, c16 = idx & 7;
    int cs = c16 ^ (r & 7);
    offA[i] = (long)(m0 + r) * lda + cs * 8;
    offB[i] = (long)(n0 + r) * ldb + cs * 8;
    ldsoff[i] = idx * 8;
  }
  long k_beg = (long)sid * k_len;
  int NT = k_len / 64;

  auto stage = [&](int buf, long k0) {
#pragma unroll
    for (int i = 0; i < 4; i++)
      gload16(A + offA[i] + k0, &lA[buf][ldsoff[i]]);
#pragma unroll
    for (int i = 0; i < 4; i++)
      gload16(Bm + offB[i] + k0, &lB[buf][ldsoff[i]]);
  };

#define AFRAG(rr, kk) (*reinterpret_cast<const bf16x8*>( \
    &lA[cur][(rr) * 64 + ((((kk) * 4 + lkg) ^ ((rr) & 7)) << 3)]))
#define BFRAG(rr, kk) (*reinterpret_cast<const bf16x8*>( \
    &lB[cur][(rr) * 64 + ((((kk) * 4 + lkg) ^ ((rr) & 7)) << 3)]))

  // prologue
  stage(0, k_beg);
  asm volatile("s_waitcnt vmcnt(0)" ::: "memory");
  __builtin_amdgcn_s_barrier();
  __builtin_amdgcn_sched_barrier(0);

  bf16x8 af[4][2], bfr[4][2];
  int cur = 0;
  for (int t = 0; t < NT; ++t) {
    // ---------- phase 0: stage next tile; A-half0 + B n0-1; MFMA q0 --------
    if (t + 1 < NT) stage(cur ^ 1, k_beg + (long)(t + 1) * 64);
#pragma unroll
    for (int m = 0; m < 4; m++) {
      int rr = wm * 128 + m * 16 + lr;
      af[m][0] = AFRAG(rr, 0); af[m][1] = AFRAG(rr, 1);
    }
#pragma unroll
    for (int n = 0; n < 2; n++) {
      int rr = wn * 64 + n * 16 + lr;
      bfr[n][0] = BFRAG(rr, 0); bfr[n][1] = BFRAG(rr, 1);
    }
    asm volatile("s_waitcnt lgkmcnt(0)" ::: "memory");
    __builtin_amdgcn_sched_barrier(0);
    __builtin_amdgcn_s_setprio(1);
#pragma unroll
    for (int m = 0; m < 4; m++)
#pragma unroll
      for (int n = 0; n < 2; n++) {
        acc[m][n] = __builtin_amdgcn_mfma_f32_16x16x32_bf16(af[m][0], bfr[n][0], acc[m][n], 0, 0, 0);
        acc[m][n] = __builtin_amdgcn_mfma_f32_16x16x32_bf16(af[m][1], bfr[n][1], acc[m][n], 0, 0, 0);
      }
    __builtin_amdgcn_s_setprio(0);
    __builtin_amdgcn_s_barrier();
    __builtin_amdgcn_sched_barrier(0);
    // ---------- phase 1: B n2-3; MFMA q1 -----------------------------------
#pragma unroll
    for (int n = 2; n < 4; n++) {
      int rr = wn * 64 + n * 16 + lr;
      bfr[n][0] = BFRAG(rr, 0); bfr[n][1] = BFRAG(rr, 1);
    }
    asm volatile("s_waitcnt lgkmcnt(0)" ::: "memory");
    __builtin_amdgcn_sched_barrier(0);
    __builtin_amdgcn_s_setprio(1);
#pragma unroll
    for (int m = 0; m < 4; m++)
#pragma unroll
      for (int n = 2; n < 4; n++) {
        acc[m][n] = __builtin_amdgcn_mfma_f32_16x16x32_bf16(af[m][0], bfr[n][0], acc[m][n], 0, 0, 0);
        acc[m][n] = __builtin_amdgcn_mfma_f32_16x16x32_bf16(af[m][1], bfr[n][1], acc[m][n], 0, 0, 0);
      }
    __builtin_amdgcn_s_setprio(0);
    __builtin_amdgcn_s_barrier();
    __builtin_amdgcn_sched_barrier(0);
    // ---------- phase 2: A-half1; MFMA q2 ----------------------------------
#pragma unroll
    for (int m = 0; m < 4; m++) {
      int rr = wm * 128 + 64 + m * 16 + lr;
      af[m][0] = AFRAG(rr, 0); af[m][1] = AFRAG(rr, 1);
    }
    asm volatile("s_waitcnt lgkmcnt(0)" ::: "memory");
    __builtin_amdgcn_sched_barrier(0);
    __builtin_amdgcn_s_setprio(1);
#pragma unroll
    for (int m = 0; m < 4; m++)
#pragma unroll
      for (int n = 2; n < 4; n++) {
        acc[m + 4][n] = __builtin_amdgcn_mfma_f32_16x16x32_bf16(af[m][0], bfr[n][0], acc[m + 4][n], 0, 0, 0);
        acc[m + 4][n] = __builtin_amdgcn_mfma_f32_16x16x32_bf16(af[m][1], bfr[n][1], acc[m + 4][n], 0, 0, 0);
      }
    __builtin_amdgcn_s_setprio(0);
    __builtin_amdgcn_s_barrier();
    __builtin_amdgcn_sched_barrier(0);
    // ---------- phase 3: no reads; MFMA q3; tile-boundary sync -------------
    __builtin_amdgcn_s_setprio(1);
#pragma unroll
    for (int m = 0; m < 4; m++)
#pragma unroll
      for (int n = 0; n < 2; n++) {
        acc[m + 4][n] = __builtin_amdgcn_mfma_f32_16x16x32_bf16(af[m][0], bfr[n][0], acc[m + 4][n], 0, 0, 0);
        acc[m + 4][n] = __builtin_amdgcn_mfma_f32_16x16x32_bf16(af[m][1], bfr[n][1], acc[m + 4][n], 0, 0, 0);
      }
    __builtin_amdgcn_s_setprio(0);
    asm volatile("s_waitcnt vmcnt(0)" ::: "memory");  // own stages landed
    __builtin_amdgcn_s_barrier();                     // all waves' stages landed
    __builtin_amdgcn_sched_barrier(0);
    cur ^= 1;
  }
#undef AFRAG
#undef BFRAG

  // epilogue
#pragma unroll
  for (int m = 0; m < 8; m++)
#pragma unroll
    for (int n = 0; n < 4; n++)
#pragma unroll
      for (int j = 0; j < 4; j++) {
        long row = m0 + wm * 128 + m * 16 + lkg * 4 + j;
        long col = n0 + wn * 64 + n * 16 + lr;
        float v = acc[m][n][j];
        if (MODE == 0) {
          long colT = col + ncol_off;
          float g = gelu_exact(v + biasv[colT]);
          float pw = P[row * NL_ + (int)(colT >> 11)];
          ((u16*)outp)[row * ldo + col] = f2bf(g * pw);
        } else if (MODE == 1) {
          ((float*)outp)[((long)sid * B_ + row) * O_ + col] = v;
        } else {
          float prev = accum ? ((float*)outp)[row * O_ + col] : 0.f;
          float bsum;
          if (expert >= 0) {
            bsum = P[row * NL_ + expert] * biasv[expert * O_ + col];
          } else {
            bsum = 0.f;
#pragma unroll
            for (int e = 0; e < NL_; e++)
              bsum += P[row * NL_ + e] * biasv[e * O_ + col];
          }
          ((float*)outp)[row * O_ + col] = prev + v + bsum;
        }
      }
}

// ---- y = Ypart0 + Ypart1 + sum_e P[b][e]*eb2[e][:] ------------------------
__global__ __launch_bounds__(256) void reduce_kernel(
    const float* __restrict__ Yp, const float* __restrict__ P,
    const float* __restrict__ eb2, float* __restrict__ y) {
  size_t i = ((size_t)blockIdx.x * 256 + threadIdx.x) * 4;
  size_t row = i >> 10;
  int col = (int)(i & 1023);
  f32x4 a = *reinterpret_cast<const f32x4*>(Yp + i);
  f32x4 b = *reinterpret_cast<const f32x4*>(Yp + (size_t)B_ * O_ + i);
  f32x4 s = a + b;
#pragma unroll
  for (int e = 0; e < NL_; e++) {
    float pe = P[row * NL_ + e];
    f32x4 w = *reinterpret_cast<const f32x4*>(eb2 + (size_t)e * O_ + col);
    s += w * pe;
  }
  *reinterpret_cast<f32x4*>(y + i) = s;
}

extern "C" void kernel_launch(void* const* d_in, const int* in_sizes, int n_in,
                              void* d_out, int out_size, void* d_ws, size_t ws_size,
                              hipStream_t stream) {
  (void)in_sizes; (void)n_in; (void)out_size;
  const float* x   = (const float*)d_in[0];
  const float* rW1 = (const float*)d_in[1];
  const float* rb1 = (const float*)d_in[2];
  const float* rW2 = (const float*)d_in[3];
  const float* rb2 = (const float*)d_in[4];
  const float* eW1 = (const float*)d_in[5];
  const float* eb1 = (const float*)d_in[6];
  const float* eW2 = (const float*)d_in[7];
  const float* eb2 = (const float*)d_in[8];
  const int*  topk = (const int*)d_in[9];
  float* y = (float*)d_out;
  float* P = y + (size_t)B_ * O_;   // leaf_probs live in d_out tail

  char* ws = (char*)d_ws;
  size_t off = 0;
  auto take = [&](size_t bytes) {
    size_t o = off; off += (bytes + 255) & ~(size_t)255; return o;
  };
  // Ypart (64MB) aliases [W1t | Xb3-head] (80MB) — both dead before gemm2.
  float* Ypart = (float*)ws;
  u16*  W1t = (u16*)(ws + take((size_t)NL_ * HE_ * D_ * 2));    // 32 MB
  u16*  Xb3 = (u16*)(ws + take((size_t)B_ * K3_ * 2));          // 48 MB
  u16*  W2t = (u16*)(ws + take((size_t)O_ * NL_ * HE_ * 2));    // 32 MB
  u16*  Wr3 = (u16*)(ws + take((size_t)256 * K3_ * 2));         // 1.5 MB
  float* H1 = (float*)(ws + take((size_t)B_ * RC_ * 4));        // 7 MB
  size_t hc = off;
  u16* Hcat = (u16*)(ws + hc);
  bool fused = (hc + (size_t)B_ * NL_ * HE_ * 2) <= ws_size;    // +268 MB

  build_xb3_kernel<<<(B_ * D_) / 1024, 256, 0, stream>>>(x, Xb3);
  build_wr3_kernel<<<(256 * K3_) / 1024, 256, 0, stream>>>(rW1, Wr3);
  // W1t[e*HE+n][k] = eW1[e][k][n]
  transpose_cvt_kernel<<<dim3(HE_ / 64, D_ / 64, NL_), 256, 0, stream>>>(
      eW1, W1t, D_, HE_, D_, (long)D_ * HE_, (long)HE_ * D_);
  // W2t[o][e*HE+h] = eW2[e][h][o]
  transpose_cvt_kernel<<<dim3(O_ / 64, HE_ / 64, NL_), 256, 0, stream>>>(
      eW2, W2t, HE_, O_, NL_ * HE_, (long)HE_ * O_, (long)HE_);
  router_gemm_kernel<<<128, 256, 0, stream>>>(Xb3, Wr3, rb1, H1);
  router_logits_kernel<<<B_ / 256, 256, 0, stream>>>(H1, rW2, rb2, topk, P);

  if (fused) {
    // GEMM1: [8192,1024] x [16384,1024]^T -> Hcat bf16 (gelu, p-scaled)
    gemm8p_kernel<0><<<2048, 512, 0, stream>>>(
        Xb3, W1t, eb1, P, Hcat, K3_, D_, 32, 64, NL_ * HE_, 0, -1, 0, D_);
    // GEMM2 split-K=2: [8192,16384] x [1024,16384]^T -> Ypart f32
    gemm8p_kernel<1><<<256, 512, 0, stream>>>(
        Hcat, W2t, nullptr, P, Ypart, NL_ * HE_, NL_ * HE_, 32, 4, O_, 0, -1, 0,
        NL_ * HE_ / 2);
    reduce_kernel<<<(B_ * O_) / 1024, 256, 0, stream>>>(Ypart, P, eb2, y);
  } else {
    // per-expert loop (He[8192][2048] in Hcat slot)
    u16* He = Hcat;
    for (int e = 0; e < NL_; e++) {
      gemm8p_kernel<0><<<256, 512, 0, stream>>>(
          Xb3, W1t + (size_t)e * HE_ * D_, eb1, P, He, K3_, D_, 32, 8, HE_,
          e * HE_, -1, 0, D_);
      gemm8p_kernel<2><<<128, 512, 0, stream>>>(
          He, W2t + (size_t)e * HE_, eb2, P, y, HE_, NL_ * HE_, 32, 4, O_, 0,
          e, (e > 0), HE_);
    }
  }
}

// Round 3
// 934.502 us; speedup vs baseline: 1.3685x; 1.3685x over previous
//
#include <hip/hip_runtime.h>
#include <hip/hip_bf16.h>
#include <cstdint>

// Problem dims (fixed by the reference)
#define B_   8192
#define D_   1024
#define O_   1024
#define HE_  2048
#define NN_  7     // decision nodes
#define NL_  8     // leaves / experts
#define HR_  32    // router hidden
#define RC_  224   // NN_*HR_
#define K3_  3072  // router split-GEMM K (hi|hi|lo)

typedef __attribute__((ext_vector_type(2))) float f32x2;
typedef __attribute__((ext_vector_type(4))) float f32x4;
typedef __attribute__((ext_vector_type(8))) short bf16x8;
typedef __attribute__((ext_vector_type(4))) unsigned short u16x4;
typedef unsigned short u16;
typedef unsigned int u32;

__device__ __forceinline__ u16 f2bf(float f) {
  __hip_bfloat16 h = __float2bfloat16(f);
  return *reinterpret_cast<u16*>(&h);
}
__device__ __forceinline__ float bf2f(u16 u) {
  u32 v = ((u32)u) << 16;
  return *reinterpret_cast<float*>(&v);
}
__device__ __forceinline__ float gelu_exact(float v) {
  return 0.5f * v * (1.0f + erff(v * 0.7071067811865475f));
}
__device__ __forceinline__ void gload16(const void* g, void* l) {
  __builtin_amdgcn_global_load_lds(
      (const __attribute__((address_space(1))) void*)(uintptr_t)g,
      (__attribute__((address_space(3))) void*)(uintptr_t)l,
      16, 0, 0);
}
#define WAITVM(n) asm volatile("s_waitcnt vmcnt(" #n ")" ::: "memory")

// ---- Xb3[b][3072] = [bf16(x) | bf16(x) | bf16(x - bf16(x))] ---------------
__global__ __launch_bounds__(256) void build_xb3_kernel(
    const float* __restrict__ in, u16* __restrict__ out) {
  size_t i = ((size_t)blockIdx.x * 256 + threadIdx.x) * 4;
  size_t row = i >> 10;
  int col = (int)(i & 1023);
  f32x4 f = *reinterpret_cast<const f32x4*>(in + i);
  u16x4 hi, lo;
#pragma unroll
  for (int j = 0; j < 4; j++) {
    hi[j] = f2bf(f[j]);
    lo[j] = f2bf(f[j] - bf2f(hi[j]));
  }
  u16* base = out + row * (size_t)K3_ + col;
  *reinterpret_cast<u16x4*>(base)        = hi;
  *reinterpret_cast<u16x4*>(base + 1024) = hi;
  *reinterpret_cast<u16x4*>(base + 2048) = lo;
}

// ---- Wr3[256][3072]: rows c<224 = [w_hi | w_lo | w_hi] of rW1[n][k][h] ----
__global__ __launch_bounds__(256) void build_wr3_kernel(
    const float* __restrict__ rW1, u16* __restrict__ Wr3) {
  size_t i = ((size_t)blockIdx.x * 256 + threadIdx.x) * 4;  // over 256*3072
  int c = (int)(i / K3_), k = (int)(i % K3_);
  int j = k >> 10, kk = k & 1023;
  u16x4 o;
  if (c < RC_) {
    int node = c >> 5, h = c & 31;
    const float* src = rW1 + ((size_t)node * 1024 + kk) * HR_ + h;
#pragma unroll
    for (int t = 0; t < 4; t++) {
      float f = src[t * HR_];
      u16 hi = f2bf(f);
      o[t] = (j == 1) ? f2bf(f - bf2f(hi)) : hi;
    }
  } else {
    o[0] = 0; o[1] = 0; o[2] = 0; o[3] = 0;
  }
  *reinterpret_cast<u16x4*>(Wr3 + i) = o;
}

// ------------- transpose + cvt: out[c*ldo + r] (+e*out_estride) = in[r][c] --
__global__ __launch_bounds__(256) void transpose_cvt_kernel(
    const float* __restrict__ in, u16* __restrict__ out,
    int R, int C, int ldo, long in_estride, long out_estride) {
  __shared__ __attribute__((aligned(16))) float tile[64][65];
  const float* in_e = in + (long)blockIdx.z * in_estride;
  u16* out_e = out + (long)blockIdx.z * out_estride;
  int t = threadIdx.x;
  int r0 = blockIdx.y * 64, c0 = blockIdx.x * 64;
  int cc = t & 63, rbase = t >> 6;
#pragma unroll
  for (int i = 0; i < 16; i++) {
    int rr = rbase + i * 4;
    tile[rr][cc] = in_e[(long)(r0 + rr) * C + c0 + cc];
  }
  __syncthreads();
  int r2 = (t & 31) * 2, cj = t >> 5;
#pragma unroll
  for (int i = 0; i < 8; i++) {
    int c = cj * 8 + i;
    u32 u = (u32)f2bf(tile[r2][c]) | ((u32)f2bf(tile[r2 + 1][c]) << 16);
    *reinterpret_cast<u32*>(out_e + (long)(c0 + c) * ldo + r0 + r2) = u;
  }
}

// ---- router GEMM (m97 128x128 structure): H1 = gelu(Xb3 @ Wr3^T + rb1) ----
__global__ __launch_bounds__(256, 2) void router_gemm_kernel(
    const u16* __restrict__ A, const u16* __restrict__ Bm,
    const float* __restrict__ rb1, float* __restrict__ H1) {
  __shared__ __attribute__((aligned(16))) u16 lA[128 * 32];
  __shared__ __attribute__((aligned(16))) u16 lB[128 * 32];
  int tid = threadIdx.x;
  int gid = blockIdx.x;
  int cpx = gridDim.x >> 3;
  gid = (gid & 7) * cpx + (gid >> 3);
  int bandsz = 2 * 8;
  int band = gid / bandsz, inb = gid % bandsz;
  long m0 = (long)(band * 8 + (inb & 7)) * 128;
  long n0 = (long)(inb >> 3) * 128;
  int wid = tid >> 6, lane = tid & 63;
  int wm = wid >> 1, wn = wid & 1;
  f32x4 acc[4][4];
#pragma unroll
  for (int m = 0; m < 4; m++)
#pragma unroll
    for (int n = 0; n < 4; n++) acc[m][n] = (f32x4){0.f, 0.f, 0.f, 0.f};
  int lr = lane & 15, lk = (lane >> 4) * 8;
  int srow = tid >> 2, soff = (tid & 3) * 8;
  const u16* Ab = A + m0 * K3_;
  const u16* Bb = Bm + n0 * K3_;
  for (int k0 = 0; k0 < K3_; k0 += 32) {
    gload16(Ab + (long)srow * K3_ + k0 + soff, &lA[tid * 8]);
    gload16(Ab + (long)(64 + srow) * K3_ + k0 + soff, &lA[(256 + tid) * 8]);
    gload16(Bb + (long)srow * K3_ + k0 + soff, &lB[tid * 8]);
    gload16(Bb + (long)(64 + srow) * K3_ + k0 + soff, &lB[(256 + tid) * 8]);
    __syncthreads();
    bf16x8 af[4], bfr[4];
#pragma unroll
    for (int m = 0; m < 4; m++)
      af[m] = *reinterpret_cast<const bf16x8*>(&lA[(wm * 64 + m * 16 + lr) * 32 + lk]);
#pragma unroll
    for (int n = 0; n < 4; n++)
      bfr[n] = *reinterpret_cast<const bf16x8*>(&lB[(wn * 64 + n * 16 + lr) * 32 + lk]);
#pragma unroll
    for (int m = 0; m < 4; m++)
#pragma unroll
      for (int n = 0; n < 4; n++)
        acc[m][n] = __builtin_amdgcn_mfma_f32_16x16x32_bf16(af[m], bfr[n], acc[m][n], 0, 0, 0);
    __syncthreads();
  }
  int lq = lane >> 4;
#pragma unroll
  for (int m = 0; m < 4; m++)
#pragma unroll
    for (int n = 0; n < 4; n++)
#pragma unroll
      for (int j = 0; j < 4; j++) {
        long row = m0 + wm * 64 + m * 16 + lq * 4 + j;
        long col = n0 + wn * 64 + n * 16 + lr;
        if (col < RC_)
          H1[row * RC_ + col] = gelu_exact(acc[m][n][j] + rb1[col]);
      }
}

// -------- router layer 2 + softmax + path products + top-k + renorm --------
__global__ __launch_bounds__(256) void router_logits_kernel(
    const float* __restrict__ H1, const float* __restrict__ rW2,
    const float* __restrict__ rb2, const int* __restrict__ topk_ptr,
    float* __restrict__ P) {
  int b = blockIdx.x * 256 + threadIdx.x;
  const float* hrow = H1 + (long)b * RC_;
  float dec[NN_][2];
#pragma unroll
  for (int n = 0; n < NN_; n++) {
    float l0 = rb2[n * 2], l1 = rb2[n * 2 + 1];
#pragma unroll
    for (int r4 = 0; r4 < HR_; r4 += 4) {
      f32x4 h = *reinterpret_cast<const f32x4*>(hrow + n * HR_ + r4);
#pragma unroll
      for (int j = 0; j < 4; j++) {
        l0 += h[j] * rW2[(n * HR_ + r4 + j) * 2];
        l1 += h[j] * rW2[(n * HR_ + r4 + j) * 2 + 1];
      }
    }
    float mx = fmaxf(l0, l1);
    float e0 = expf(l0 - mx), e1 = expf(l1 - mx);
    float s = e0 + e1;
    dec[n][0] = e0 / s; dec[n][1] = e1 / s;
  }
  float v[NL_];
#pragma unroll
  for (int L = 0; L < NL_; L++)
    v[L] = dec[0][L >> 2] * dec[1 + (L >> 2)][(L >> 1) & 1] * dec[3 + (L >> 1)][L & 1];
  int tk = *topk_ptr;
  float p[NL_];
  if (tk < NL_) {
    float s = 0.f;
    bool keep[NL_];
#pragma unroll
    for (int e = 0; e < NL_; e++) {
      int rank = 0;
#pragma unroll
      for (int j = 0; j < NL_; j++)
        rank += ((v[j] > v[e]) || (v[j] == v[e] && j < e)) ? 1 : 0;
      keep[e] = rank < tk;
      if (keep[e]) s += v[e];
    }
    float inv = 1.f / (s + 1e-8f);
#pragma unroll
    for (int e = 0; e < NL_; e++) p[e] = keep[e] ? v[e] * inv : 0.f;
  } else {
#pragma unroll
    for (int e = 0; e < NL_; e++) p[e] = v[e];
  }
#pragma unroll
  for (int e = 0; e < NL_; e++) P[(long)b * NL_ + e] = p[e];
}

// ---- y init: y[b][o] = sum_e P[b][e]*eb2[e][o] ----------------------------
__global__ __launch_bounds__(256) void yinit_kernel(
    const float* __restrict__ P, const float* __restrict__ eb2,
    float* __restrict__ y) {
  size_t i = ((size_t)blockIdx.x * 256 + threadIdx.x) * 4;
  size_t row = i >> 10;
  int col = (int)(i & 1023);
  f32x4 s = (f32x4){0.f, 0.f, 0.f, 0.f};
#pragma unroll
  for (int e = 0; e < NL_; e++) {
    float pe = P[row * NL_ + e];
    f32x4 w = *reinterpret_cast<const f32x4*>(eb2 + (size_t)e * O_ + col);
    s += w * pe;
  }
  *reinterpret_cast<f32x4*>(y + i) = s;
}

// ============ quad-buffered counted-vmcnt MFMA GEMM (T2+T3+T4+T5) ==========
// BK=32, BN=256, 8 waves (2M x 4N). 4 LDS buffers, prefetch depth 3,
// ONE s_barrier per K-tile, vmcnt counted (never 0 in steady state).
// Chunk swizzle pos=(c+((r>>1)&3))&3 on pre-permuted global source + reads.
// MODE 0: BM=256; out bf16 H = bf16(gelu(acc+eb1[col+off]) * P[row][expert])
// MODE 2: BM=128; out f32  y[row][col] += acc   (y pre-initialized w/ bias)
template<int MODE>
__global__ __launch_bounds__(512, 2) void gemmq_kernel(
    const u16* __restrict__ A, const u16* __restrict__ Bm,
    const float* __restrict__ eb1, const float* __restrict__ P,
    void* __restrict__ outp, int lda, int ldb, int ldo,
    int tiles_n, int ncol_off, int NT) {
  constexpr int AFR = (MODE == 0) ? 8 : 4;   // A frags/wave (16 rows each)
  constexpr int BM  = AFR * 32;              // 256 or 128
  constexpr int ABUF = BM * 32;              // elems per A buffer
  constexpr int BBUF = 256 * 32;
  constexpr int APT = ABUF / (8 * 512);      // A gloads/thread/tile: 2 or 1
  __shared__ __attribute__((aligned(16))) u16 lA[4][ABUF];
  __shared__ __attribute__((aligned(16))) u16 lB[4][BBUF];

  int tid = threadIdx.x;
  int gid = blockIdx.x;
  int cpx = gridDim.x >> 3;
  gid = (gid & 7) * cpx + (gid >> 3);        // bijective XCD swizzle (grid%8==0)
  int bandsz = tiles_n * 8;
  int band = gid / bandsz, inb = gid % bandsz;
  long m0 = (long)(band * 8 + (inb & 7)) * BM;
  long n0 = (long)(inb >> 3) * 256;
  int wid = tid >> 6, lane = tid & 63;
  int wm = wid >> 2, wn = wid & 3;           // 2M x 4N
  int lr = lane & 15, lkg = lane >> 4;

  f32x4 acc[AFR][4];
#pragma unroll
  for (int m = 0; m < AFR; m++)
#pragma unroll
    for (int n = 0; n < 4; n++) acc[m][n] = (f32x4){0.f, 0.f, 0.f, 0.f};

  // staging addresses: LDS position (r, j) holds global chunk (j - s_r)&3,
  // s_r = (r>>1)&3  (inverse of the read-side mapping below)
  long offA[APT]; int ldsA[APT];
#pragma unroll
  for (int i = 0; i < APT; i++) {
    int idx = tid + i * 512;
    int r = idx >> 2, j = idx & 3;
    int c = (j + 4 - ((r >> 1) & 3)) & 3;
    offA[i] = (long)(m0 + r) * lda + c * 8;
    ldsA[i] = idx * 8;
  }
  long offB[2]; int ldsB[2];
#pragma unroll
  for (int i = 0; i < 2; i++) {
    int idx = tid + i * 512;
    int r = idx >> 2, j = idx & 3;
    int c = (j + 4 - ((r >> 1) & 3)) & 3;
    offB[i] = (long)(n0 + r) * ldb + c * 8;
    ldsB[i] = idx * 8;
  }
  // read-side frag byte offsets: logical chunk lkg of row r at pos=(lkg+s_r)&3
  int foA[AFR], foB[4];
#pragma unroll
  for (int m = 0; m < AFR; m++) {
    int r = wm * (AFR * 16) + m * 16 + lr;
    foA[m] = r * 64 + (((lkg + ((r >> 1) & 3)) & 3) << 4);
  }
#pragma unroll
  for (int n = 0; n < 4; n++) {
    int r = wn * 64 + n * 16 + lr;
    foB[n] = r * 64 + (((lkg + ((r >> 1) & 3)) & 3) << 4);
  }

  auto stage = [&](int buf, int kt) {
    long kk = (long)kt << 5;
#pragma unroll
    for (int i = 0; i < APT; i++)
      gload16(A + offA[i] + kk, &lA[buf][ldsA[i]]);
#pragma unroll
    for (int i = 0; i < 2; i++)
      gload16(Bm + offB[i] + kk, &lB[buf][ldsB[i]]);
  };

  stage(0, 0); stage(1, 1); stage(2, 2);     // 3 tiles in flight

  for (int t = 0; t < NT; ++t) {
    if (t + 2 < NT) {
      if constexpr (MODE == 0) WAITVM(8); else WAITVM(6);   // 2 tiles out
    } else if (t + 1 < NT) {
      if constexpr (MODE == 0) WAITVM(4); else WAITVM(3);   // 1 tile out
    } else {
      WAITVM(0);
    }
    __builtin_amdgcn_s_barrier();            // raw: no vmcnt(0) drain
    __builtin_amdgcn_sched_barrier(0);
    if (t + 3 < NT) stage((t + 3) & 3, t + 3);
    const char* pa = (const char*)lA[t & 3];
    const char* pb = (const char*)lB[t & 3];
    bf16x8 af[AFR], bfr[4];
#pragma unroll
    for (int m = 0; m < AFR; m++)
      af[m] = *reinterpret_cast<const bf16x8*>(pa + foA[m]);
#pragma unroll
    for (int n = 0; n < 4; n++)
      bfr[n] = *reinterpret_cast<const bf16x8*>(pb + foB[n]);
    asm volatile("s_waitcnt lgkmcnt(0)" ::: "memory");
    __builtin_amdgcn_sched_barrier(0);
    __builtin_amdgcn_s_setprio(1);
#pragma unroll
    for (int m = 0; m < AFR; m++)
#pragma unroll
      for (int n = 0; n < 4; n++)
        acc[m][n] = __builtin_amdgcn_mfma_f32_16x16x32_bf16(af[m], bfr[n], acc[m][n], 0, 0, 0);
    __builtin_amdgcn_s_setprio(0);
    __builtin_amdgcn_sched_barrier(0);
  }

  // epilogue
#pragma unroll
  for (int m = 0; m < AFR; m++)
#pragma unroll
    for (int n = 0; n < 4; n++)
#pragma unroll
      for (int j = 0; j < 4; j++) {
        long row = m0 + wm * (AFR * 16) + m * 16 + lkg * 4 + j;
        long col = n0 + wn * 64 + n * 16 + lr;
        float v = acc[m][n][j];
        if (MODE == 0) {
          long colT = col + ncol_off;
          float g = gelu_exact(v + eb1[colT]);
          float pw = P[row * NL_ + (int)(colT >> 11)];
          ((u16*)outp)[row * ldo + col] = f2bf(g * pw);
        } else {
          ((float*)outp)[row * ldo + col] += v;
        }
      }
}

extern "C" void kernel_launch(void* const* d_in, const int* in_sizes, int n_in,
                              void* d_out, int out_size, void* d_ws, size_t ws_size,
                              hipStream_t stream) {
  (void)in_sizes; (void)n_in; (void)out_size;
  const float* x   = (const float*)d_in[0];
  const float* rW1 = (const float*)d_in[1];
  const float* rb1 = (const float*)d_in[2];
  const float* rW2 = (const float*)d_in[3];
  const float* rb2 = (const float*)d_in[4];
  const float* eW1 = (const float*)d_in[5];
  const float* eb1 = (const float*)d_in[6];
  const float* eW2 = (const float*)d_in[7];
  const float* eb2 = (const float*)d_in[8];
  const int*  topk = (const int*)d_in[9];
  float* y = (float*)d_out;
  float* P = y + (size_t)B_ * O_;   // leaf_probs live in d_out tail

  char* ws = (char*)d_ws;
  u16*  Xb3 = (u16*)ws;                                   // 48 MiB
  u16*  W1t = (u16*)(ws + 50331648);                      // 32 MiB
  u16*  W2t = (u16*)(ws + 83886080);                      // 32 MiB
  char* hreg = ws + 117440512;                            // Hbuf region
  u16*  Hbuf = (u16*)hreg;
  u16*  Wr3  = (u16*)hreg;                                // dead before Hbuf use
  float* H1  = (float*)(hreg + 1572864);

  // experts-per-group: largest that fits ws (base 112MiB + EPG*32MiB)
  int epg = 1;
  {
    const size_t base = 117440512, per = 33554432;
    if      (base + 8 * per <= ws_size) epg = 8;
    else if (base + 4 * per <= ws_size) epg = 4;
    else if (base + 2 * per <= ws_size) epg = 2;
  }

  build_xb3_kernel<<<(B_ * D_) / 1024, 256, 0, stream>>>(x, Xb3);
  build_wr3_kernel<<<(256 * K3_) / 1024, 256, 0, stream>>>(rW1, Wr3);
  // W1t[e*HE+n][k] = eW1[e][k][n]
  transpose_cvt_kernel<<<dim3(HE_ / 64, D_ / 64, NL_), 256, 0, stream>>>(
      eW1, W1t, D_, HE_, D_, (long)D_ * HE_, (long)HE_ * D_);
  // W2t[o][e*HE+h] = eW2[e][h][o]
  transpose_cvt_kernel<<<dim3(O_ / 64, HE_ / 64, NL_), 256, 0, stream>>>(
      eW2, W2t, HE_, O_, NL_ * HE_, (long)HE_ * O_, (long)HE_);
  router_gemm_kernel<<<128, 256, 0, stream>>>(Xb3, Wr3, rb1, H1);
  router_logits_kernel<<<B_ / 256, 256, 0, stream>>>(H1, rW2, rb2, topk, P);
  yinit_kernel<<<(B_ * O_) / 1024, 256, 0, stream>>>(P, eb2, y);

  const int groups = NL_ / epg;
  for (int g = 0; g < groups; g++) {
    // GEMM1: [8192 x 1024] @ [epg*2048 x 1024]^T -> Hbuf (gelu, p-scaled)
    gemmq_kernel<0><<<32 * (epg * 8), 512, 0, stream>>>(
        Xb3, W1t + (size_t)g * epg * HE_ * D_, eb1, P, Hbuf,
        K3_, D_, epg * HE_, epg * 8, g * epg * HE_, 32);
    // GEMM2: [8192 x epg*2048] @ [1024 x epg*2048]^T  accumulated into y
    gemmq_kernel<2><<<64 * 4, 512, 0, stream>>>(
        Hbuf, W2t + (size_t)g * epg * HE_, nullptr, nullptr, y,
        epg * HE_, NL_ * HE_, O_, 4, 0, epg * 64);
  }
}